// Round 1
// baseline (48.168 us; speedup 1.0000x reference)
//
#include <hip/hip_runtime.h>

#define IW 512
#define IH 512
#define NPLANES 24      // B*C = 8*3
#define NSTEPS 7

// two adjacent floats, only dword-aligned (compiler may fuse to dwordx2;
// CDNA global loads only need dword alignment)
struct f2u { float x, y; };

__global__ __launch_bounds__(256) void zoomblur_kernel(
    const float* __restrict__ img,
    const float* __restrict__ zoomf,
    float* __restrict__ out)
{
    const int pix = blockIdx.x * blockDim.x + threadIdx.x;   // 0 .. 512*512-1
    const int x = pix & (IW - 1);
    const int y = pix >> 9;

    const float zf = 0.85f + 0.30f * zoomf[0];
    const float dz = zf - 1.0f;

    const float xf = (float)x - 256.0f;
    const float yf = (float)y - 256.0f;

    int   off[NSTEPS - 1];
    float w00[NSTEPS - 1], w01[NSTEPS - 1], w10[NSTEPS - 1], w11[NSTEPS - 1];

#pragma unroll
    for (int s = 1; s < NSTEPS; ++s) {
        const float scale = 1.0f + ((float)s * (1.0f / 6.0f)) * dz;
        const float inv   = 1.0f / scale;
        const float xs = xf * inv + 256.0f;
        const float ys = yf * inv + 256.0f;
        const float x0f = floorf(xs);
        const float y0f = floorf(ys);
        const float wx = xs - x0f;
        const float wy = ys - y0f;
        const int x0 = (int)x0f;
        const int y0 = (int)y0f;
        // clamped pair base so both loaded columns/rows are in-bounds
        const int xb = min(max(x0, 0), IW - 2);
        const int yb = min(max(y0, 0), IH - 2);
        // remap tap weights onto slots (xb, xb+1), zeroing invalid taps
        float s0 = 0.0f, s1 = 0.0f;
        if (x0 == xb)          { s0 = 1.0f - wx; s1 = wx; }   // interior
        else if (x0 == xb - 1) { s0 = wx; }                   // x0 == -1
        else if (x0 == xb + 1) { s1 = 1.0f - wx; }            // x0 == IW-1
        float t0 = 0.0f, t1 = 0.0f;
        if (y0 == yb)          { t0 = 1.0f - wy; t1 = wy; }
        else if (y0 == yb - 1) { t0 = wy; }
        else if (y0 == yb + 1) { t1 = 1.0f - wy; }

        const int k = s - 1;
        off[k] = yb * IW + xb;
        w00[k] = s0 * t0;
        w01[k] = s1 * t0;
        w10[k] = s0 * t1;
        w11[k] = s1 * t1;
    }

    // plane loop: base pointer is wave-uniform (SGPR), offsets reused 24x
#pragma unroll 1
    for (int p = 0; p < NPLANES; ++p) {
        const float* __restrict__ base = img + (size_t)p * (IH * IW);
        float acc = base[pix];   // step 0: scale == 1 exactly -> identity
#pragma unroll
        for (int k = 0; k < NSTEPS - 1; ++k) {
            const float* r0 = base + off[k];
            const float* r1 = r0 + IW;
            const float p00 = r0[0];
            const float p01 = r0[1];
            const float p10 = r1[0];
            const float p11 = r1[1];
            acc = fmaf(w00[k], p00, acc);
            acc = fmaf(w01[k], p01, acc);
            acc = fmaf(w10[k], p10, acc);
            acc = fmaf(w11[k], p11, acc);
        }
        out[(size_t)p * (IH * IW) + pix] = acc * (1.0f / 7.0f);
    }
}

extern "C" void kernel_launch(void* const* d_in, const int* in_sizes, int n_in,
                              void* d_out, int out_size, void* d_ws, size_t ws_size,
                              hipStream_t stream) {
    const float* img  = (const float*)d_in[0];
    const float* zoom = (const float*)d_in[1];
    float* out = (float*)d_out;

    const int npix = IH * IW;               // 262144
    dim3 block(256);
    dim3 grid(npix / 256);                  // 1024 blocks
    zoomblur_kernel<<<grid, block, 0, stream>>>(img, zoom, out);
}